// Round 8
// baseline (75.522 us; speedup 1.0000x reference)
//
#include <hip/hip_runtime.h>
#include <hip/hip_bf16.h>
#include <cmath>

#define BS 4
#define NP 8192
#define FD 512
#define SM 2048
#define LOG2E10 14.4269504088896340736f  // 10 * log2(e)  (tau=0.1 folded)
#define LN2 0.6931471805599453f

typedef __attribute__((ext_vector_type(8))) short short8;
typedef __attribute__((ext_vector_type(4))) float f32x4;

static __device__ __forceinline__ unsigned short f2bf(float f) {
  unsigned u = __float_as_uint(f);
  unsigned r = u + 0x7fffu + ((u >> 16) & 1u);  // RTNE
  return (unsigned short)(r >> 16);
}
static __device__ __forceinline__ ushort4 f2bf4(float4 v) {
  ushort4 o;
  o.x = f2bf(v.x); o.y = f2bf(v.y); o.z = f2bf(v.z); o.w = f2bf(v.w);
  return o;
}

// ---------------------------------------------------------------------------
// Kernel 1: 1 wave per match row — gather, cos-sim, pts(+|p|^2), bf16 copies
// ---------------------------------------------------------------------------
__global__ __launch_bounds__(256) void stats_k(
    const float* __restrict__ velo_feat, const float* __restrict__ velo_pts,
    const float* __restrict__ ref_feat, const int* __restrict__ matches,
    float4* __restrict__ pts4, float* __restrict__ dpos,
    unsigned short* __restrict__ Abf, unsigned short* __restrict__ Pbf)
{
  const int row = blockIdx.x * 4 + (threadIdx.x >> 6);  // b*SM + s
  const int lane = threadIdx.x & 63;
  const int b = row >> 11;  // / SM
  const int ai = matches[2 * row + 0];
  const int pi = matches[2 * row + 1];

  const float4* ar = (const float4*)(velo_feat + ((size_t)b * NP + ai) * FD);
  const float4* pr = (const float4*)(ref_feat + ((size_t)b * NP + pi) * FD);
  float4 a0 = ar[lane], a1 = ar[lane + 64];
  float4 p0 = pr[lane], p1 = pr[lane + 64];

  *(ushort4*)(Abf + (size_t)row * FD + lane * 4) = f2bf4(a0);
  *(ushort4*)(Abf + (size_t)row * FD + 256 + lane * 4) = f2bf4(a1);
  *(ushort4*)(Pbf + (size_t)row * FD + lane * 4) = f2bf4(p0);
  *(ushort4*)(Pbf + (size_t)row * FD + 256 + lane * 4) = f2bf4(p1);

  float dot = a0.x * p0.x + a0.y * p0.y + a0.z * p0.z + a0.w * p0.w +
              a1.x * p1.x + a1.y * p1.y + a1.z * p1.z + a1.w * p1.w;
  float na = a0.x * a0.x + a0.y * a0.y + a0.z * a0.z + a0.w * a0.w +
             a1.x * a1.x + a1.y * a1.y + a1.z * a1.z + a1.w * a1.w;
  float nb = p0.x * p0.x + p0.y * p0.y + p0.z * p0.z + p0.w * p0.w +
             p1.x * p1.x + p1.y * p1.y + p1.z * p1.z + p1.w * p1.w;
#pragma unroll
  for (int off = 32; off; off >>= 1) {
    dot += __shfl_xor(dot, off);
    na += __shfl_xor(na, off);
    nb += __shfl_xor(nb, off);
  }
  if (lane == 0) {
    dpos[row] = dot / fmaxf(sqrtf(na) * sqrtf(nb), 1e-8f);
    const float* pp = velo_pts + ((size_t)b * NP + ai) * 3;
    float x = pp[0], y = pp[1], z = pp[2];
    pts4[row] = make_float4(x, y, z, x * x + y * y + z * z);
  }
}

// ---------------------------------------------------------------------------
// Kernel 2: 256x256 MFMA GEMM, 8-phase-style schedule (4 phases/K-tile,
// counted vmcnt(6), 3 half-tiles always in flight), 8 waves (2Mx4N),
// 128 KB LDS [buf][khalf], paired-row XOR swizzle (both-sides), setprio
// around MFMA clusters, in-lane row-LSE epilogue, bijective XCD swizzle.
// grid = 256 x 512.
// ---------------------------------------------------------------------------
__global__ __launch_bounds__(512) void tile_k(
    const unsigned short* __restrict__ Abf, const unsigned short* __restrict__ Pbf,
    const float4* __restrict__ pts4,
    float* __restrict__ maxs, float* __restrict__ sums)
{
  __shared__ unsigned short As[2][2][8192];  // [buf][khalf][16KB] = 64 KB
  __shared__ unsigned short Bs[2][2][8192];  // 64 KB

  // XCD swizzle: 256 blocks % 8 == 0 -> contiguous 32-block slab per XCD
  const int wg = ((blockIdx.x & 7) << 5) + (blockIdx.x >> 3);
  const int b = wg >> 6;
  const int stile = (wg >> 3) & 7;
  const int ctile = wg & 7;
  const int s0 = stile * 256, c0 = ctile * 256;

  const int tid = threadIdx.x;
  const int wid = tid >> 6, lane = tid & 63;
  const int wr = wid >> 2, wc = wid & 3;  // 2 x 4 wave grid -> 128x64 / wave
  const int cg = lane >> 4, cr = lane & 15;

  const char* Ab = (const char*)(Abf + ((size_t)b * SM + s0) * FD);
  const char* Bb = (const char*)(Pbf + ((size_t)b * SM + c0) * FD);

  // staging source offsets (per thread, i=0,1): inverse of the LDS swizzle.
  // LDS map: (panel row r, byte col cb in [0,64)) -> q=r>>1,
  //   byte = q*128 + ((((r&1)<<6)|cb) ^ ((q&7)<<4))
  int srcoff[2];
#pragma unroll
  for (int i = 0; i < 2; i++) {
    const int L = i * 8192 + tid * 16;
    const int q = L >> 7;
    const int inner = (L & 127) ^ ((q & 7) << 4);
    const int r = (q << 1) | (inner >> 6);
    const int c = inner & 63;
    srcoff[i] = r * (FD * 2) + c;
  }

  // stage one 16KB half-tile (128B/thread = 2 DMA loads) of K-tile kt
#define STAGEH(X, Xb, kt, kh, bufi)                                           \
  do {                                                                        \
    _Pragma("unroll") for (int i = 0; i < 2; i++) {                           \
      __builtin_amdgcn_global_load_lds(                                       \
          (const __attribute__((address_space(1))) void*)(                    \
              Xb + srcoff[i] + (kt) * 128 + (kh) * 64),                       \
          (__attribute__((address_space(3))) void*)(                          \
              (char*)&X[bufi][kh][0] + i * 8192 + wid * 1024),                \
          16, 0, 0);                                                          \
    }                                                                         \
  } while (0)

#define WAITDS()                                          \
  do {                                                    \
    asm volatile("s_waitcnt lgkmcnt(0)" ::: "memory");    \
    __builtin_amdgcn_sched_barrier(0);                    \
  } while (0)

#define BAR()                                             \
  do {                                                    \
    __builtin_amdgcn_s_barrier();                         \
    __builtin_amdgcn_sched_barrier(0);                    \
  } while (0)

  f32x4 acc[4][8];  // [n][m]
#pragma unroll
  for (int n = 0; n < 4; n++)
#pragma unroll
    for (int m = 0; m < 8; m++) acc[n][m] = (f32x4){0.f, 0.f, 0.f, 0.f};

  short8 af[4], bfr[4];

  auto LDB_ = [&](int bufi, int kh) {
#pragma unroll
    for (int n = 0; n < 4; n++) {
      const int r = wc * 64 + n * 16 + cr;
      const int q = r >> 1;
      const int v = ((((r & 1) << 6) | (cg << 4)) ^ ((q & 7) << 4));
      bfr[n] = *(const short8*)((const char*)&Bs[bufi][kh][0] + q * 128 + v);
    }
  };
  auto LDA_ = [&](int bufi, int kh, int mg) {
#pragma unroll
    for (int j = 0; j < 4; j++) {
      const int r = wr * 128 + (mg * 4 + j) * 16 + cr;
      const int q = r >> 1;
      const int v = ((((r & 1) << 6) | (cg << 4)) ^ ((q & 7) << 4));
      af[j] = *(const short8*)((const char*)&As[bufi][kh][0] + q * 128 + v);
    }
  };
  auto MFMA16_ = [&](int mg) {
    __builtin_amdgcn_s_setprio(1);
#pragma unroll
    for (int n = 0; n < 4; n++)
#pragma unroll
      for (int j = 0; j < 4; j++)
        acc[n][mg * 4 + j] = __builtin_amdgcn_mfma_f32_16x16x32_bf16(
            bfr[n], af[j], acc[n][mg * 4 + j], 0, 0, 0);
    __builtin_amdgcn_s_setprio(0);
  };

  // prologue: stage K-tile 0 (order: A-K0, B-K0, A-K1, B-K1)
  STAGEH(As, Ab, 0, 0, 0);
  STAGEH(Bs, Bb, 0, 0, 0);
  STAGEH(As, Ab, 0, 1, 0);
  STAGEH(Bs, Bb, 0, 1, 0);

#pragma unroll 1
  for (int kt = 0; kt < 8; ++kt) {
    const int bufi = kt & 1, nbuf = bufi ^ 1;
    // ---- phase 0: needs A-K0,B-K0 of kt; stages A-K0 of kt+1 ----
    if (kt < 7) {
      STAGEH(As, Ab, kt + 1, 0, nbuf);
      asm volatile("s_waitcnt vmcnt(6)" ::: "memory");  // 3 half-tiles in flight
    } else {
      asm volatile("s_waitcnt vmcnt(4)" ::: "memory");  // drain kt7 A0,B0
    }
    BAR();
    LDB_(bufi, 0);
    LDA_(bufi, 0, 0);
    WAITDS();
    MFMA16_(0);
    // ---- phase 1: reuses B-K0; stages B-K0 of kt+1 ----
    if (kt < 7) STAGEH(Bs, Bb, kt + 1, 0, nbuf);
    LDA_(bufi, 0, 1);
    WAITDS();
    MFMA16_(1);
    // ---- phase 2: needs A-K1,B-K1 of kt; stages A-K1 of kt+1 ----
    if (kt < 7) {
      STAGEH(As, Ab, kt + 1, 1, nbuf);
      asm volatile("s_waitcnt vmcnt(6)" ::: "memory");
    } else {
      asm volatile("s_waitcnt vmcnt(0)" ::: "memory");  // last tile only
    }
    BAR();
    LDB_(bufi, 1);
    LDA_(bufi, 1, 0);
    WAITDS();
    MFMA16_(0);
    // ---- phase 3: reuses B-K1; stages B-K1 of kt+1 ----
    if (kt < 7) STAGEH(Bs, Bb, kt + 1, 1, nbuf);
    LDA_(bufi, 1, 1);
    WAITDS();
    MFMA16_(1);
    BAR();  // all reads of buf[kt&1] drained before kt+1 overwrites nbuf... and
            // before kt+2's staging (issued at kt+1 p0) can touch buf[kt&1]
  }

  // ---- epilogue: in-lane row LSE. lane holds D[s][t] for s = s0+wr*128+
  // m*16+cr (m=0..7), t = c0+wc*64+n*16+cg*4+reg ----
  const float4* rpg = pts4 + (size_t)b * SM + s0 + wr * 128;
  const float4* cpg = pts4 + (size_t)b * SM + c0 + wc * 64;
  float4 rv[8];
#pragma unroll
  for (int m = 0; m < 8; m++) rv[m] = rpg[m * 16 + cr];

  float mx[8];
#pragma unroll
  for (int m = 0; m < 8; m++) mx[m] = -INFINITY;
#pragma unroll
  for (int n = 0; n < 4; n++) {
#pragma unroll
    for (int reg = 0; reg < 4; reg++) {
      float4 cv = cpg[n * 16 + cg * 4 + reg];
#pragma unroll
      for (int m = 0; m < 8; m++) {
        float dot = rv[m].x * cv.x + rv[m].y * cv.y + rv[m].z * cv.z;
        float d2 = rv[m].w + cv.w - 2.f * dot;
        float l = (d2 > 25.f) ? acc[n][m][reg] * LOG2E10 : -INFINITY;
        acc[n][m][reg] = l;
        mx[m] = fmaxf(mx[m], l);
      }
    }
  }
  float mxc[8], sm[8];
#pragma unroll
  for (int m = 0; m < 8; m++) {
    mx[m] = fmaxf(mx[m], __shfl_xor(mx[m], 16));
    mx[m] = fmaxf(mx[m], __shfl_xor(mx[m], 32));
    mxc[m] = fmaxf(mx[m], -1e37f);  // finite subtrahend if row all-masked
    sm[m] = 0.f;
  }
#pragma unroll
  for (int n = 0; n < 4; n++)
#pragma unroll
    for (int reg = 0; reg < 4; reg++)
#pragma unroll
      for (int m = 0; m < 8; m++)
        sm[m] += exp2f(acc[n][m][reg] - mxc[m]);  // exp2(-inf)=0
#pragma unroll
  for (int m = 0; m < 8; m++) {
    sm[m] += __shfl_xor(sm[m], 16);
    sm[m] += __shfl_xor(sm[m], 32);
  }
  if (cg == 0) {
    const int ct32 = ctile * 4 + wc;
    size_t base = ((size_t)ct32 * BS + b) * SM + s0 + wr * 128;
#pragma unroll
    for (int m = 0; m < 8; m++) {
      maxs[base + m * 16 + cr] = mx[m];
      sums[base + m * 16 + cr] = sm[m];
    }
  }
#undef STAGEH
#undef WAITDS
#undef BAR
}

// ---------------------------------------------------------------------------
// Kernel 3: per-row LSE merge + loss, per-block f64 partial (32 blocks)
// ---------------------------------------------------------------------------
__global__ __launch_bounds__(256) void rowloss_k(
    const float* __restrict__ dpos, const float* __restrict__ maxs,
    const float* __restrict__ sums, double* __restrict__ partial)
{
  const int r = blockIdx.x * 256 + threadIdx.x;
  float l0 = dpos[r] * LOG2E10;
  float M = l0;
#pragma unroll 8
  for (int c = 0; c < 32; c++) M = fmaxf(M, maxs[(size_t)c * BS * SM + r]);
  float s = exp2f(l0 - M);
#pragma unroll 8
  for (int c = 0; c < 32; c++) {
    float mc = maxs[(size_t)c * BS * SM + r];
    float sc = sums[(size_t)c * BS * SM + r];
    s += sc * exp2f(mc - M);  // mc=-inf -> sc=0, exp2=0 -> 0 (no nan)
  }
  double v = (double)(LN2 * (M + log2f(s) - l0));
#pragma unroll
  for (int off = 32; off; off >>= 1) v += __shfl_down(v, off);
  __shared__ double red[4];
  if ((threadIdx.x & 63) == 0) red[threadIdx.x >> 6] = v;
  __syncthreads();
  if (threadIdx.x == 0)
    partial[blockIdx.x] = red[0] + red[1] + red[2] + red[3];
}

// ---------------------------------------------------------------------------
// Kernel 4: final mean over 32 partials (1 tiny block)
// ---------------------------------------------------------------------------
__global__ __launch_bounds__(64) void final_k(const double* __restrict__ partial,
                                              float* __restrict__ out)
{
  const int t = threadIdx.x;
  double v = (t < 32) ? partial[t] : 0.0;
#pragma unroll
  for (int off = 32; off; off >>= 1) v += __shfl_down(v, off);
  if (t == 0) out[0] = (float)(v / (double)(BS * SM));
}

// ---------------------------------------------------------------------------
extern "C" void kernel_launch(void* const* d_in, const int* in_sizes, int n_in,
                              void* d_out, int out_size, void* d_ws, size_t ws_size,
                              hipStream_t stream)
{
  const float* velo_feat = (const float*)d_in[0];
  const float* velo_pts  = (const float*)d_in[1];
  const float* ref_feat  = (const float*)d_in[2];
  const int*   matches   = (const int*)d_in[3];

  // ws layout: Abf(8MB) | Pbf(8MB) | pts4(128K) | dpos(32K) | maxs(1M) | sums(1M) | partial
  char* ws = (char*)d_ws;
  const size_t NBF = (size_t)BS * SM * FD * 2;
  unsigned short* Abf = (unsigned short*)ws;
  unsigned short* Pbf = (unsigned short*)(ws + NBF);
  float4* pts4 = (float4*)(ws + 2 * NBF);
  float*  dpos = (float*)(ws + 2 * NBF + (size_t)BS * SM * 16);
  float*  maxs = (float*)(ws + 2 * NBF + (size_t)BS * SM * 20);
  float*  sums = (float*)(ws + 2 * NBF + (size_t)BS * SM * 20 + (size_t)32 * BS * SM * 4);
  double* partial = (double*)(ws + 2 * NBF + (size_t)BS * SM * 20 + (size_t)64 * BS * SM * 4);

  stats_k<<<BS * SM / 4, 256, 0, stream>>>(velo_feat, velo_pts, ref_feat,
                                           matches, pts4, dpos, Abf, Pbf);
  tile_k<<<256, 512, 0, stream>>>(Abf, Pbf, pts4, maxs, sums);
  rowloss_k<<<BS * SM / 256, 256, 0, stream>>>(dpos, maxs, sums, partial);
  final_k<<<1, 64, 0, stream>>>(partial, (float*)d_out);
}